// Round 5
// baseline (208.036 us; speedup 1.0000x reference)
//
#include <hip/hip_runtime.h>

#define NROW 8192
#define DIM  256
#define INV_T 5.0f
#define BM 128
#define BN 128
#define CSPLIT 8
#define COLS_PER_BLOCK (NROW / CSPLIT)   // 1024
#define NT 8

typedef _Float16 f16x8 __attribute__((ext_vector_type(8)));
typedef _Float16 f16x4 __attribute__((ext_vector_type(4)));
typedef float    f32x4 __attribute__((ext_vector_type(4)));
typedef unsigned long long u64;

__device__ __forceinline__ void gload_lds16(const void* g, void* l) {
  __builtin_amdgcn_global_load_lds(
      (__attribute__((address_space(1))) void*)(g),
      (__attribute__((address_space(3))) void*)(l),
      16, 0, 0);
}

// ---------------- normalize rows + convert to fp16 ----------------
__global__ __launch_bounds__(256) void norm_kernel(
    const float* __restrict__ zv, const float* __restrict__ zf,
    _Float16* __restrict__ ov, _Float16* __restrict__ of) {
  const float* in  = blockIdx.y ? zf : zv;
  _Float16*    out = blockIdx.y ? of : ov;
  int row  = blockIdx.x * 4 + (threadIdx.x >> 6);
  int lane = threadIdx.x & 63;
  float4 v = ((const float4*)(in + (size_t)row * DIM))[lane];
  float ss = v.x * v.x + v.y * v.y + v.z * v.z + v.w * v.w;
#pragma unroll
  for (int off = 1; off < 64; off <<= 1) ss += __shfl_xor(ss, off);
  float inv = 1.0f / fmaxf(sqrtf(ss), 1e-12f);
  f16x4 o;
  o.x = (_Float16)(v.x * inv);
  o.y = (_Float16)(v.y * inv);
  o.z = (_Float16)(v.z * inv);
  o.w = (_Float16)(v.w * inv);
  ((f16x4*)(out + (size_t)row * DIM))[lane] = o;
}

// ---------------- main kernel: G-blocks (dense GEMM+exp) + S-blocks (sparse Gf scan) ----
// bid: cb = bid&7 (XCD-affine column slice), kind = (bid>>3)&1, rb = bid>>4.
__global__ __launch_bounds__(256, 2) void main_kernel(
    const _Float16* __restrict__ zv, const _Float16* __restrict__ zf,
    const float* __restrict__ Gf,
    float* __restrict__ Ep, float* __restrict__ Pp,
    float* __restrict__ sEp, float* __restrict__ Cp) {

  __shared__ __align__(16) _Float16 Asf[BM * DIM];      // 64 KB
  __shared__ __align__(16) _Float16 Bs[2][BN * 32];     // 16 KB

  const int bid  = blockIdx.x;
  const int cb   = bid & 7;
  const int kind = (bid >> 3) & 1;
  const int rb   = bid >> 4;
  const int t_   = threadIdx.x;
  const int lane = t_ & 63;
  const int row0 = rb * BM;
  const int col0 = cb * COLS_PER_BLOCK;

  if (kind == 0) {
    // =================== G-block: E_i partials over 1024 cols ===================
    const int w   = t_ >> 6;
    const int wr  = w >> 1;
    const int wc  = w & 1;
    const int l15 = lane & 15;
    const int kq  = lane >> 4;

    // stage full A tile (128 x 256 fp16), source pre-swizzled
#pragma unroll
    for (int c = 0; c < 16; ++c) {
      int i = c * 256 + t_;
      int row = i >> 5, cbP = i & 31;
      int cbL = cbP ^ (row & 7);
      gload_lds16(zv + (size_t)(row0 + row) * DIM + cbL * 8,
                  &Asf[(size_t)(c * 256 + w * 64) * 8]);
    }

    auto stageB = [&](int buf, int s) {
      int tt = s >> 3, kk = s & 7;
      int ct0 = col0 + tt * BN;
      int k0 = kk * 32;
#pragma unroll
      for (int c = 0; c < 2; ++c) {
        int i = c * 256 + t_;
        int row = i >> 2, cbP = i & 3;
        int cbL = cbP ^ ((row >> 1) & 3);
        gload_lds16(zf + (size_t)(ct0 + row) * DIM + k0 + cbL * 8,
                    &Bs[buf][(size_t)(c * 256 + w * 64) * 8]);
      }
    };

    stageB(0, 0);
    asm volatile("s_waitcnt vmcnt(0)" ::: "memory");
    __syncthreads();

    f32x4 acc[4][4];
    float Sa[16];
#pragma unroll
    for (int i = 0; i < 16; ++i) Sa[i] = 0.0f;

#pragma unroll 2
    for (int s = 0; s < 64; ++s) {
      const int cur = s & 1;
      if ((s & 7) == 0) {
#pragma unroll
        for (int m = 0; m < 4; ++m)
#pragma unroll
          for (int n = 0; n < 4; ++n) acc[m][n] = (f32x4)(0.0f);
      }
      if (s < 63) stageB(cur ^ 1, s + 1);

      const int k0 = (s & 7) * 32;
      f16x8 af[4], bf[4];
#pragma unroll
      for (int m = 0; m < 4; ++m) {
        int row = wr * 64 + m * 16 + l15;
        int cbL = (k0 >> 3) + kq;
        int cbP = cbL ^ (row & 7);
        af[m] = *(const f16x8*)&Asf[(size_t)row * 256 + cbP * 8];
      }
#pragma unroll
      for (int n = 0; n < 4; ++n) {
        int row = wc * 64 + n * 16 + l15;
        int cbP = kq ^ ((row >> 1) & 3);
        bf[n] = *(const f16x8*)&Bs[cur][(size_t)row * 32 + cbP * 8];
      }
#pragma unroll
      for (int m = 0; m < 4; ++m)
#pragma unroll
        for (int n = 0; n < 4; ++n)
          acc[m][n] = __builtin_amdgcn_mfma_f32_16x16x32_f16(af[m], bf[n], acc[m][n], 0, 0, 0);

      if ((s & 7) == 7) {
#pragma unroll
        for (int m = 0; m < 4; ++m)
#pragma unroll
          for (int n = 0; n < 4; ++n)
#pragma unroll
            for (int r = 0; r < 4; ++r)
              Sa[m * 4 + r] += __expf(acc[m][n][r] * INV_T);
      }
      asm volatile("s_waitcnt vmcnt(0)" ::: "memory");
      __builtin_amdgcn_s_barrier();
    }

    // reduce across the 16 column-lanes of each row group
#pragma unroll
    for (int off = 1; off <= 8; off <<= 1)
#pragma unroll
      for (int i = 0; i < 16; ++i) Sa[i] += __shfl_xor(Sa[i], off);

    const int slot = cb * 2 + wc;   // 16 slots
#pragma unroll
    for (int i = 0; i < 16; ++i) {
      if (l15 == i) {
        int m = i >> 2, r = i & 3;
        int row = row0 + wr * 64 + m * 16 + kq * 4 + r;
        Ep[(size_t)slot * NROW + row] = Sa[i];
      }
    }
  } else {
    // =================== S-block: sparse Gf scan over 128 x 1024 slice ===================
    const int wv = t_ >> 6;                 // wave 0..3: rows [wv*32, wv*32+32)
    const int rowbase = row0 + wv * 32;

    float4 bufA[4], bufB[4];
    const float* gbase = Gf + (size_t)rowbase * NROW + col0 + lane * 4;

    auto issueRow = [&](float4* q, int r) {
      const float* p = gbase + (size_t)r * NROW;
#pragma unroll
      for (int c = 0; c < 4; ++c) q[c] = *(const float4*)(p + c * 256);
    };

    auto procRow = [&](const float4* q, int r) {
      const int i = rowbase + r;
      // preload zv row fragment
      f16x4 a16 = *(const f16x4*)(zv + (size_t)i * DIM + lane * 4);
      float a0 = (float)a16[0], a1 = (float)a16[1], a2 = (float)a16[2], a3 = (float)a16[3];
      float P = 0.0f, E = 0.0f, C = 0.0f;
#pragma unroll
      for (int c = 0; c < 4; ++c) {
        float4 qq = q[c];
        int j0 = col0 + lane * 4 + c * 256;
        bool any = (qq.x > 0.0f) | (qq.y > 0.0f) | (qq.z > 0.0f) | (qq.w > 0.0f);
        bool dg = ((unsigned)(i - j0)) < 4u;
        u64 b = __ballot(any || dg);
        while (b) {
          int L = (int)__builtin_ctzll(b);
          b &= b - 1;
          float g0 = __shfl(qq.x, L), g1 = __shfl(qq.y, L);
          float g2 = __shfl(qq.z, L), g3 = __shfl(qq.w, L);
          int j0L = col0 + L * 4 + c * 256;
#pragma unroll
          for (int cc = 0; cc < 4; ++cc) {
            float g = (cc == 0) ? g0 : (cc == 1) ? g1 : (cc == 2) ? g2 : g3;
            int jj = j0L + cc;
            if (g > 0.0f || jj == i) {     // wave-uniform branch
              f16x4 b16 = *(const f16x4*)(zf + (size_t)jj * DIM + lane * 4);
              float d = a0 * (float)b16[0] + a1 * (float)b16[1] +
                        a2 * (float)b16[2] + a3 * (float)b16[3];
#pragma unroll
              for (int off = 1; off < 64; off <<= 1) d += __shfl_xor(d, off);
              float sim = d * INV_T;
              P += sim;
              E += __expf(sim);
              C += 1.0f;
            }
          }
        }
      }
      if (lane == 0) {
        Pp [(size_t)cb * NROW + i] = P;
        sEp[(size_t)cb * NROW + i] = E;
        Cp [(size_t)cb * NROW + i] = C;
      }
    };

    issueRow(bufA, 0);
    asm volatile("" ::: "memory");
#pragma unroll 1
    for (int r = 0; r < 32; r += 2) {
      if (r + 1 < 32) issueRow(bufB, r + 1);
      asm volatile("" ::: "memory");
      procRow(bufA, r);
      if (r + 2 < 32) issueRow(bufA, r + 2);
      asm volatile("" ::: "memory");
      if (r + 1 < 32) procRow(bufB, r + 1);
    }
  }
}

// ---------------- per-row loss + block partials (deterministic) ----------------
__global__ __launch_bounds__(256) void loss_partial_kernel(
    const float* __restrict__ Ep, const float* __restrict__ Pp,
    const float* __restrict__ sEp, const float* __restrict__ Cp,
    float* __restrict__ bsum) {
  int row = blockIdx.x * 256 + threadIdx.x;
  float E = 0.0f, P = 0.0f, sE = 0.0f, C = 0.0f;
#pragma unroll
  for (int s2 = 0; s2 < 16; ++s2) E += Ep[(size_t)s2 * NROW + row];
#pragma unroll
  for (int s2 = 0; s2 < 8; ++s2) {
    P  += Pp [(size_t)s2 * NROW + row];
    sE += sEp[(size_t)s2 * NROW + row];
    C  += Cp [(size_t)s2 * NROW + row];
  }
  float S = E - sE + C;                 // neg exps + one per pos slot
  float pos = P / (C + 1e-8f);
  float contrib = __logf(S + __expf(pos)) - pos;
#pragma unroll
  for (int off = 1; off < 64; off <<= 1) contrib += __shfl_xor(contrib, off);
  __shared__ float wsum[4];
  if ((threadIdx.x & 63) == 0) wsum[threadIdx.x >> 6] = contrib;
  __syncthreads();
  if (threadIdx.x == 0) bsum[blockIdx.x] = wsum[0] + wsum[1] + wsum[2] + wsum[3];
}

__global__ void loss_final_kernel(const float* __restrict__ bsum, float* __restrict__ out) {
  int lane = threadIdx.x;
  float v = (lane < 32) ? bsum[lane] : 0.0f;
#pragma unroll
  for (int off = 1; off < 64; off <<= 1) v += __shfl_xor(v, off);
  if (lane == 0) out[0] = v / (float)NROW;
}

extern "C" void kernel_launch(void* const* d_in, const int* in_sizes, int n_in,
                              void* d_out, int out_size, void* d_ws, size_t ws_size,
                              hipStream_t stream) {
  const float* zv = (const float*)d_in[0];
  const float* zf = (const float*)d_in[1];
  const float* Gf = (const float*)d_in[2];
  float* out = (float*)d_out;

  char* ws = (char*)d_ws;
  _Float16* zv16 = (_Float16*)ws;                          // 4 MB
  _Float16* zf16 = zv16 + (size_t)NROW * DIM;              // 4 MB
  float* Ep  = (float*)(ws + 2 * (size_t)NROW * DIM * sizeof(_Float16));
  float* Pp  = Ep  + 16 * (size_t)NROW;
  float* sEp = Pp  + 8 * (size_t)NROW;
  float* Cp  = sEp + 8 * (size_t)NROW;
  float* bsum = Cp + 8 * (size_t)NROW;

  norm_kernel<<<dim3(NROW / 4, 2), 256, 0, stream>>>(zv, zf, zv16, zf16);
  main_kernel<<<1024, 256, 0, stream>>>(zv16, zf16, Gf, Ep, Pp, sEp, Cp);
  loss_partial_kernel<<<NROW / 256, 256, 0, stream>>>(Ep, Pp, sEp, Cp, bsum);
  loss_final_kernel<<<1, 64, 0, stream>>>(bsum, out);
}

// Round 6
// 116.998 us; speedup vs baseline: 1.7781x; 1.7781x over previous
//
#include <hip/hip_runtime.h>

#define NROW 8192
#define DIM  256
#define INV_T 5.0f

typedef _Float16 f16x8 __attribute__((ext_vector_type(8)));
typedef _Float16 f16x4 __attribute__((ext_vector_type(4)));
typedef float    f32x4 __attribute__((ext_vector_type(4)));
typedef unsigned long long u64;

__device__ __forceinline__ void gload_lds16(const void* g, void* l) {
  __builtin_amdgcn_global_load_lds(
      (__attribute__((address_space(1))) void*)(g),
      (__attribute__((address_space(3))) void*)(l),
      16, 0, 0);
}

// ---------------- normalize rows + convert to fp16 ----------------
__global__ __launch_bounds__(256) void norm_kernel(
    const float* __restrict__ zv, const float* __restrict__ zf,
    _Float16* __restrict__ ov, _Float16* __restrict__ of) {
  const float* in  = blockIdx.y ? zf : zv;
  _Float16*    out = blockIdx.y ? of : ov;
  int row  = blockIdx.x * 4 + (threadIdx.x >> 6);
  int lane = threadIdx.x & 63;
  float4 v = ((const float4*)(in + (size_t)row * DIM))[lane];
  float ss = v.x * v.x + v.y * v.y + v.z * v.z + v.w * v.w;
#pragma unroll
  for (int off = 1; off < 64; off <<= 1) ss += __shfl_xor(ss, off);
  float inv = 1.0f / fmaxf(sqrtf(ss), 1e-12f);
  f16x4 o;
  o.x = (_Float16)(v.x * inv);
  o.y = (_Float16)(v.y * inv);
  o.z = (_Float16)(v.z * inv);
  o.w = (_Float16)(v.w * inv);
  ((f16x4*)(out + (size_t)row * DIM))[lane] = o;
}

// Gf load into static ring slot (slot = L & 7), and ballot-pack 4 steps later.
#define GFLOAD(SLOT, L, TT)                                                    \
  qv[SLOT] = *(const float4*)(Gf + (size_t)(grow + 2 * (L)) * NROW + gcol + (TT) * 128)

#define PACKB(SLOT, L, TT, G)                                                  \
  do {                                                                         \
    int d_ = (grow + 2 * (L)) - (gcol + (TT) * 128);                           \
    float4 q_ = qv[SLOT];                                                      \
    u64 b0_ = __ballot(q_.x > 0.0f || d_ == 0);                                \
    u64 b1_ = __ballot(q_.y > 0.0f || d_ == 1);                                \
    u64 b2_ = __ballot(q_.z > 0.0f || d_ == 2);                                \
    u64 b3_ = __ballot(q_.w > 0.0f || d_ == 3);                                \
    u64 s01_ = (l15 & 1) ? b1_ : b0_;                                          \
    u64 s23_ = (l15 & 1) ? b3_ : b2_;                                          \
    u64 bs_ = (l15 & 2) ? s23_ : s01_;                                         \
    if (kq == (((L) >> 1) & 3)) G[(L) >> 3][(L) & 1] = bs_;                    \
  } while (0)

// ---------------- fused GEMM + Gf-mask + exp/row-reductions ----------------
// 256 blocks (1/CU), 512 threads (8 waves, each owning 32 rows x 128-col tiles).
// B triple-buffered, staged 2 ahead, counted vmcnt(5) per step (no drains).
// Gf pipelined 4 steps deep through an 8-slot float4 ring -> ballot masks.
__global__ __launch_bounds__(512, 2) void fused_kernel(
    const _Float16* __restrict__ zv, const _Float16* __restrict__ zf,
    const float* __restrict__ Gf,
    float* __restrict__ Sp, float* __restrict__ Pp, float* __restrict__ Cp) {

  __shared__ __align__(16) _Float16 Asf[256 * 256];   // 128 KB, XOR-swizzled
  __shared__ __align__(16) _Float16 Bsf[3 * 128 * 32]; // 24 KB, 3 buffers

  const int t_   = threadIdx.x;
  const int lane = t_ & 63;
  const int w    = t_ >> 6;          // 0..7, wave owns rows [w*32, w*32+32)
  const int l15  = lane & 15;
  const int kq   = lane >> 4;
  const int bx   = blockIdx.x >> 3;  // 0..31
  const int cb   = blockIdx.x & 7;   // XCD-affine column slice
  const int row0 = bx * 256;
  const int col0 = cb * 1024;

  const int grow = row0 + w * 32 + (lane >> 5);
  const int gcol = col0 + (lane & 31) * 4;

  // ---- stage full A tile (256 x 256 fp16), source pre-swizzled ----
#pragma unroll
  for (int c = 0; c < 16; ++c) {
    int i = c * 512 + t_;
    int arow = i >> 5, cbP = i & 31;
    int cbL = cbP ^ (arow & 7);
    gload_lds16(zv + (size_t)(row0 + arow) * DIM + cbL * 8,
                &Asf[(size_t)(c * 512 + w * 64) * 8]);
  }

  auto stageB = [&](int bufidx, int tt, int kk) {
    int row = t_ >> 2, cbP = t_ & 3;
    int cbL = cbP ^ ((row >> 1) & 3);
    gload_lds16(zf + (size_t)(col0 + tt * 128 + row) * DIM + kk * 32 + cbL * 8,
                &Bsf[(size_t)bufidx * 4096 + w * 512]);
  };

  float4 qv[8];
  u64 gm[2][2], gn[2][2];

  stageB(0, 0, 0);
  stageB(1, 0, 1);
  // tile-0 masks built in prologue
#pragma unroll
  for (int L = 0; L < 8; ++L) GFLOAD(L, L, 0);
#pragma unroll
  for (int L = 0; L < 8; ++L) PACKB(L, L, 0, gm);
#pragma unroll
  for (int L = 8; L < 16; ++L) GFLOAD((L) & 7, L, 0);
#pragma unroll
  for (int L = 8; L < 16; ++L) PACKB((L) & 7, L, 0, gm);
  asm volatile("s_waitcnt vmcnt(0)" ::: "memory");
  __builtin_amdgcn_s_barrier();

  f32x4 acc[2][8];
  float Sa[8], Pa[8], Ca[8];
#pragma unroll
  for (int i = 0; i < 8; ++i) { Sa[i] = 0.0f; Pa[i] = 0.0f; Ca[i] = 0.0f; }

#define STEP(KK)                                                               \
  do {                                                                         \
    if (t == 7) {                                                              \
      if ((KK) == 0)      asm volatile("s_waitcnt vmcnt(5)" ::: "memory");     \
      else if ((KK) == 1) asm volatile("s_waitcnt vmcnt(3)" ::: "memory");     \
      else if ((KK) == 7) asm volatile("s_waitcnt vmcnt(0)" ::: "memory");     \
      else                asm volatile("s_waitcnt vmcnt(1)" ::: "memory");     \
    } else {                                                                   \
      asm volatile("s_waitcnt vmcnt(5)" ::: "memory");                         \
    }                                                                          \
    __builtin_amdgcn_s_barrier();                                              \
    const _Float16* Bb = &Bsf[((b0i + (KK)) % 3) * 4096];                      \
    f16x8 bf[8], af[2];                                                        \
    _Pragma("unroll") for (int n = 0; n < 8; ++n) {                            \
      int brow = n * 16 + l15;                                                 \
      int ph = kq ^ ((brow >> 1) & 3);                                         \
      bf[n] = *(const f16x8*)&Bb[brow * 32 + ph * 8];                          \
    }                                                                          \
    _Pragma("unroll") for (int m = 0; m < 2; ++m) {                            \
      int arow = w * 32 + m * 16 + l15;                                        \
      int ap = ((KK) * 4 + kq) ^ (arow & 7);                                   \
      af[m] = *(const f16x8*)&Asf[(size_t)arow * 256 + ap * 8];                \
    }                                                                          \
    if ((KK) <= 3) {                                                           \
      if (t >= 1) {                                                            \
        PACKB((2 * (KK)) & 7, 8 + 2 * (KK), t, gn);                            \
        PACKB((2 * (KK) + 1) & 7, 9 + 2 * (KK), t, gn);                        \
      }                                                                        \
    } else if (t < 7) {                                                        \
      PACKB((2 * (KK)) & 7, 2 * ((KK) - 4), t + 1, gn);                        \
      PACKB((2 * (KK) + 1) & 7, 2 * ((KK) - 4) + 1, t + 1, gn);                \
    }                                                                          \
    if ((KK) == 3 && t >= 1) {                                                 \
      gm[0][0] = gn[0][0]; gm[0][1] = gn[0][1];                                \
      gm[1][0] = gn[1][0]; gm[1][1] = gn[1][1];                                \
    }                                                                          \
    { int s2 = t * 8 + (KK) + 2;                                               \
      if (s2 <= 63) stageB((b0i + (KK) + 2) % 3, s2 >> 3, s2 & 7); }           \
    asm volatile("" ::: "memory");                                             \
    if (t < 7) {                                                               \
      GFLOAD((2 * (KK)) & 7, 2 * (KK), t + 1);                                 \
      GFLOAD((2 * (KK) + 1) & 7, 2 * (KK) + 1, t + 1);                         \
    }                                                                          \
    asm volatile("" ::: "memory");                                             \
    if ((KK) == 0) {                                                           \
      _Pragma("unroll") for (int m = 0; m < 2; ++m)                            \
        _Pragma("unroll") for (int n = 0; n < 8; ++n) acc[m][n] = (f32x4)(0.0f); \
    }                                                                          \
    _Pragma("unroll") for (int m = 0; m < 2; ++m)                              \
      _Pragma("unroll") for (int n = 0; n < 8; ++n)                            \
        acc[m][n] = __builtin_amdgcn_mfma_f32_16x16x32_f16(                    \
            af[m], bf[n], acc[m][n], 0, 0, 0);                                 \
    if ((KK) == 7) {                                                           \
      _Pragma("unroll") for (int m = 0; m < 2; ++m)                            \
        _Pragma("unroll") for (int rh = 0; rh < 2; ++rh) {                     \
          u64 uu = gm[m][rh] >> (l15 >> 2);                                    \
          unsigned lo = (unsigned)uu, hi = (unsigned)(uu >> 32);               \
          _Pragma("unroll") for (int n = 0; n < 8; ++n)                        \
            _Pragma("unroll") for (int rl = 0; rl < 2; ++rl) {                 \
              int r = rh * 2 + rl;                                             \
              bool pos = (((rl ? hi : lo) >> (n * 4)) & 1u) != 0u;             \
              float sim = acc[m][n][r] * INV_T;                                \
              float e = __expf(sim);                                           \
              int idx = m * 4 + r;                                             \
              Sa[idx] += pos ? 1.0f : e;                                       \
              Pa[idx] += pos ? sim : 0.0f;                                     \
              Ca[idx] += pos ? 1.0f : 0.0f;                                    \
            }                                                                  \
        }                                                                      \
    }                                                                          \
  } while (0)

#pragma unroll 1
  for (int t = 0; t < 8; ++t) {
    const int b0i = (2 * t) % 3;
    STEP(0); STEP(1); STEP(2); STEP(3);
    STEP(4); STEP(5); STEP(6); STEP(7);
  }
#undef STEP

  // ---- reduce across the 16 column-lanes of each row group ----
#pragma unroll
  for (int off = 1; off <= 8; off <<= 1) {
#pragma unroll
    for (int i = 0; i < 8; ++i) {
      Sa[i] += __shfl_xor(Sa[i], off);
      Pa[i] += __shfl_xor(Pa[i], off);
      Ca[i] += __shfl_xor(Ca[i], off);
    }
  }
#pragma unroll
  for (int i = 0; i < 8; ++i) {
    if (l15 == i) {
      int m = i >> 2, r = i & 3;
      int row = row0 + w * 32 + m * 16 + kq * 4 + r;
      Sp[(size_t)cb * NROW + row] = Sa[i];
      Pp[(size_t)cb * NROW + row] = Pa[i];
      Cp[(size_t)cb * NROW + row] = Ca[i];
    }
  }
}

// ---------------- per-row loss + block partials (deterministic) ----------------
__global__ __launch_bounds__(256) void loss_partial_kernel(
    const float* __restrict__ Sp, const float* __restrict__ Pp,
    const float* __restrict__ Cp, float* __restrict__ bsum) {
  int row = blockIdx.x * 256 + threadIdx.x;
  float S = 0.0f, P = 0.0f, C = 0.0f;
#pragma unroll
  for (int s2 = 0; s2 < 8; ++s2) {
    S += Sp[(size_t)s2 * NROW + row];
    P += Pp[(size_t)s2 * NROW + row];
    C += Cp[(size_t)s2 * NROW + row];
  }
  float pos = P / (C + 1e-8f);
  float contrib = __logf(S + __expf(pos)) - pos;
#pragma unroll
  for (int off = 1; off < 64; off <<= 1) contrib += __shfl_xor(contrib, off);
  __shared__ float wsum[4];
  if ((threadIdx.x & 63) == 0) wsum[threadIdx.x >> 6] = contrib;
  __syncthreads();
  if (threadIdx.x == 0) bsum[blockIdx.x] = wsum[0] + wsum[1] + wsum[2] + wsum[3];
}

__global__ void loss_final_kernel(const float* __restrict__ bsum, float* __restrict__ out) {
  int lane = threadIdx.x;
  float v = (lane < 32) ? bsum[lane] : 0.0f;
#pragma unroll
  for (int off = 1; off < 64; off <<= 1) v += __shfl_xor(v, off);
  if (lane == 0) out[0] = v / (float)NROW;
}

extern "C" void kernel_launch(void* const* d_in, const int* in_sizes, int n_in,
                              void* d_out, int out_size, void* d_ws, size_t ws_size,
                              hipStream_t stream) {
  const float* zv = (const float*)d_in[0];
  const float* zf = (const float*)d_in[1];
  const float* Gf = (const float*)d_in[2];
  float* out = (float*)d_out;

  char* ws = (char*)d_ws;
  _Float16* zv16 = (_Float16*)ws;                          // 4 MB
  _Float16* zf16 = zv16 + (size_t)NROW * DIM;              // 4 MB
  float* Sp = (float*)(ws + 2 * (size_t)NROW * DIM * sizeof(_Float16));
  float* Pp = Sp + 8 * (size_t)NROW;
  float* Cp = Pp + 8 * (size_t)NROW;
  float* bsum = Cp + 8 * (size_t)NROW;                     // 32 floats

  norm_kernel<<<dim3(NROW / 4, 2), 256, 0, stream>>>(zv, zf, zv16, zf16);
  fused_kernel<<<256, 512, 0, stream>>>(zv16, zf16, Gf, Sp, Pp, Cp);
  loss_partial_kernel<<<NROW / 256, 256, 0, stream>>>(Sp, Pp, Cp, bsum);
  loss_final_kernel<<<1, 64, 0, stream>>>(bsum, out);
}